// Round 13
// baseline (261.231 us; speedup 1.0000x reference)
//
#include <hip/hip_runtime.h>
#include <hip/hip_bf16.h>

#define NB     2
#define NROI   1000
#define CIN    256
#define FDIM   1024
#define M_ROWS 2000          // NB*NROI
#define K1     12544         // 7*7*256
#define EPSBN  1e-3f
#define MN     (M_ROWS * FDIM)

typedef short bf16x8 __attribute__((ext_vector_type(8)));
typedef short bf16x4 __attribute__((ext_vector_type(4)));
typedef float f32x4  __attribute__((ext_vector_type(4)));

__device__ __forceinline__ void gld_lds16(const void* g, void* l) {
  __builtin_amdgcn_global_load_lds((const __attribute__((address_space(1))) char*)g,
                                   (__attribute__((address_space(3))) char*)l, 16, 0, 0);
}

// soft grid sync: all blocks co-resident (grid 256 = 1 block/CU). cnt zeroed in prep.
__device__ __forceinline__ void grid_sync(int* cnt, int nb) {
  __syncthreads();
  if (threadIdx.x == 0) {
    __threadfence();                       // prior writes+atomics visible device-wide
    atomicAdd(cnt, 1);
    while (atomicAdd(cnt, 0) < nb) { }
    __threadfence();
  }
  __syncthreads();
}

// ================= prep: zero-stats+counters | roi-align | transpose1 | transpose2 =================
// grid: [0]=zero, [1,2001)=roi, [2001,5137)=w1 tiles, [5137,5393)=w2 tiles
__global__ __launch_bounds__(256) void prep_kernel(
    const float* __restrict__ rois,
    const float* __restrict__ p2, const float* __restrict__ p3,
    const float* __restrict__ p4, const float* __restrict__ p5,
    __hip_bfloat16* __restrict__ pooled,
    const float* __restrict__ conv1_w, __hip_bfloat16* __restrict__ w1t,
    const float* __restrict__ conv2_w, __hip_bfloat16* __restrict__ w2t,
    float* __restrict__ stats) {
  __shared__ float tt[64][65];
  int idx = blockIdx.x;
  int t = threadIdx.x;

  if (idx == 0) {                      // zero stats1+stats2 (4096 floats) + 2 sync counters
#pragma unroll
    for (int i = 0; i < 4; i++)
      ((f32x4*)stats)[t + i * 256] = f32x4{0, 0, 0, 0};
    if (t < 2) ((int*)(stats + 4096))[t] = 0;
    return;
  }

  if (idx < 1 + M_ROWS) {              // ---- ROI align ----
    int rn = idx - 1;
    int b = rn / NROI;

    const float* roi = rois + (size_t)rn * 4;
    float y1 = roi[0], x1 = roi[1], y2 = roi[2], x2 = roi[3];
    float h = y2 - y1, w = x2 - x1;
    float lvl = log2f(fmaxf(sqrtf(h * w), 1e-9f) * 4.0f);   // scale 0.25 -> *4 exact
    int li = 4 + (int)rintf(lvl);
    li = min(max(li, 2), 5) - 2;

    const float* fm; int H;
    switch (li) {
      case 0:  fm = p2; H = 256; break;
      case 1:  fm = p3; H = 128; break;
      case 2:  fm = p4; H = 64;  break;
      default: fm = p5; H = 32;  break;
    }
    int W = H;
    const float* fb = fm + (size_t)b * H * W * CIN;

    int lane = t & 63, wv = t >> 6;
    int c4 = lane * 4;

    for (int pos = wv; pos < 49; pos += 4) {
      int py = pos / 7, px = pos - py * 7;
      float fy = (float)py / 6.0f, fx = (float)px / 6.0f;
      float ys = (y1 + (y2 - y1) * fy) * (float)(H - 1);
      float xs = (x1 + (x2 - x1) * fx) * (float)(W - 1);
      float y0f = floorf(ys), x0f = floorf(xs);
      float wy = ys - y0f, wx = xs - x0f;
      int y0 = min(max((int)y0f, 0), H - 1);
      int x0 = min(max((int)x0f, 0), W - 1);
      int y1i = min(y0 + 1, H - 1);
      int x1i = min(x0 + 1, W - 1);

      f32x4 v00 = *(const f32x4*)(fb + ((size_t)y0 * W + x0) * CIN + c4);
      f32x4 v01 = *(const f32x4*)(fb + ((size_t)y0 * W + x1i) * CIN + c4);
      f32x4 v10 = *(const f32x4*)(fb + ((size_t)y1i * W + x0) * CIN + c4);
      f32x4 v11 = *(const f32x4*)(fb + ((size_t)y1i * W + x1i) * CIN + c4);

      f32x4 top = v00 + (v01 - v00) * wx;
      f32x4 bot = v10 + (v11 - v10) * wx;
      f32x4 val = top + (bot - top) * wy;

      bf16x4 o;
#pragma unroll
      for (int j = 0; j < 4; j++) {
        __hip_bfloat16 hh = __float2bfloat16(val[j]);
        o[j] = *reinterpret_cast<short*>(&hh);
      }
      *(bf16x4*)((short*)pooled + ((size_t)rn * 49 + pos) * CIN + c4) = o;
    }
    return;
  }

  // ---- transpose 64x64 tile: W[K][N] -> WT[N][K] bf16 ----
  const float* W; short* WT; int K, N, bx, by;
  if (idx < 1 + M_ROWS + 3136) {
    int wk = idx - (1 + M_ROWS);
    W = conv1_w; WT = (short*)w1t; K = K1; N = FDIM;
    bx = wk % 196; by = wk / 196;
  } else {
    int wk = idx - (1 + M_ROWS + 3136);
    W = conv2_w; WT = (short*)w2t; K = FDIM; N = FDIM;
    bx = wk % 16; by = wk / 16;
  }
  int k0 = bx * 64, n0 = by * 64;
  int r = t >> 2, c = t & 3;
#pragma unroll
  for (int i = 0; i < 4; i++) {
    int cg = c * 4 + i;                 // float4 column group 0..15
    f32x4 v = *(const f32x4*)(W + (size_t)(k0 + r) * N + n0 + cg * 4);
#pragma unroll
    for (int j = 0; j < 4; j++) tt[cg * 4 + j][r] = v[j];
  }
  __syncthreads();
  int n = t >> 2, g = t & 3;
#pragma unroll
  for (int i = 0; i < 2; i++) {
    int seg = g * 2 + i;                // 8 segments of 8 bf16
    bf16x8 o;
#pragma unroll
    for (int j = 0; j < 8; j++) {
      __hip_bfloat16 hh = __float2bfloat16(tt[n][seg * 8 + j]);
      o[j] = *reinterpret_cast<short*>(&hh);
    }
    *(bf16x8*)(WT + (size_t)(n0 + n) * K + k0 + seg * 8) = o;
  }
}

// ================= 8-wave deep-pipelined GEMM (GEMM1 + GEMM2) =================
// BM=128, BN=256, BK=64 (2 kh-halves of 32). 512 thr = 8 waves (2M x 4N),
// each wave 64x64 out (4x4 16x16x32 frags). Split-K: P[ks][M][N] f32.
// LDS: A[buf][kh][128][32], B[buf][kh][256][32], slot-swizzled (g^(row&3)).
// Pipeline: 3 half-stages in flight (9 loads), vmcnt(6) boundaries.
template<int KSLICES>
__global__ __launch_bounds__(512) void gemm8w(const short* __restrict__ A,
                                              const short* __restrict__ BT,
                                              float* __restrict__ P,
                                              int M, int N, int K) {
  __shared__ short As[4 * 128 * 32];   // (buf*2+kh)*4096
  __shared__ short Bs[4 * 256 * 32];   // (buf*2+kh)*8192

  int nwg = gridDim.x;                 // divisible by 8
  int bid = blockIdx.x;
  int cpx = nwg >> 3;
  int wg = (bid & 7) * cpx + (bid >> 3);

  int MT = (M + 127) >> 7;
  int NTn = N >> 8;
  int tiles = MT * NTn;
  int ks = wg / tiles;
  int rem = wg % tiles;
  int tm = rem % MT, tn = rem / MT;
  int m0 = tm * 128, n0 = tn * 256;
  int Kc = K / KSLICES;
  int NT = Kc >> 6;                    // K-tiles of 64
  size_t kb = (size_t)ks * Kc;

  int tid = threadIdx.x;
  int lane = tid & 63, wid = tid >> 6;
  int wr = wid >> 2, wc = wid & 3;

  // staging sources (pre-swizzled): granule (row, slot) holds logical g = slot^(row&3)
  int srow = tid >> 2;
  int g = (tid & 3) ^ (srow & 3);
  const short* Agb  = A  + (size_t)min(m0 + srow, M - 1) * K + kb + g * 8;
  const short* Bgb0 = BT + (size_t)(n0 + srow) * K + kb + g * 8;
  const short* Bgb1 = Bgb0 + (size_t)128 * K;
  int aoff  = wid * 512;
  int boff0 = wid * 512;
  int boff1 = 4096 + wid * 512;

  // fragment read bases (swizzled): addr = row*32 + ((lane>>4)^(lane&3))*8
  int lr = lane & 15;
  int slotoff = ((lane >> 4) ^ (lane & 3)) * 8;
  const short* Ard = As + (wr * 64 + lr) * 32 + slotoff;
  const short* Brd = Bs + (wc * 64 + lr) * 32 + slotoff;

  f32x4 acc[4][4] = {};

#define STAGE(s) do {                                                        \
    int ts_ = (s) >> 1, kh_ = (s) & 1, b_ = ts_ & 1;                         \
    int ko_ = ts_ * 64 + kh_ * 32;                                           \
    short* Ad_ = (short*)As + (b_ * 2 + kh_) * 4096 + aoff;                  \
    short* Bd_ = (short*)Bs + (b_ * 2 + kh_) * 8192;                         \
    gld_lds16(Agb + ko_, Ad_);                                               \
    gld_lds16(Bgb0 + ko_, Bd_ + boff0);                                      \
    gld_lds16(Bgb1 + ko_, Bd_ + boff1);                                      \
  } while (0)

  STAGE(0); STAGE(1); STAGE(2);

  for (int t = 0; t < NT; ++t) {
    int b = t & 1;
#pragma unroll
    for (int kh = 0; kh < 2; ++kh) {
      __builtin_amdgcn_sched_barrier(0);
      if (t < NT - 1)      asm volatile("s_waitcnt vmcnt(6)" ::: "memory");
      else if (kh == 0)    asm volatile("s_waitcnt vmcnt(3)" ::: "memory");
      else                 asm volatile("s_waitcnt vmcnt(0)" ::: "memory");
      __builtin_amdgcn_s_barrier();
      __builtin_amdgcn_sched_barrier(0);

      const short* Ab = Ard + (b * 2 + kh) * 4096;
      const short* Bb = Brd + (b * 2 + kh) * 8192;
      bf16x8 af[4], bf_[4];
#pragma unroll
      for (int mi = 0; mi < 4; mi++) af[mi] = *(const bf16x8*)(Ab + mi * 512);
#pragma unroll
      for (int ni = 0; ni < 4; ni++) bf_[ni] = *(const bf16x8*)(Bb + ni * 512);

      if (kh == 0) { if (t + 1 < NT) STAGE(2 * t + 3); }
      else         { if (t + 2 < NT) STAGE(2 * t + 4); }

      __builtin_amdgcn_sched_barrier(0);
      asm volatile("s_waitcnt lgkmcnt(0)" ::: "memory");
      __builtin_amdgcn_sched_barrier(0);
      __builtin_amdgcn_s_setprio(1);
#pragma unroll
      for (int mi = 0; mi < 4; mi++)
#pragma unroll
        for (int ni = 0; ni < 4; ni++)
          acc[mi][ni] = __builtin_amdgcn_mfma_f32_16x16x32_bf16(af[mi], bf_[ni], acc[mi][ni], 0, 0, 0);
      __builtin_amdgcn_s_setprio(0);
    }
  }
#undef STAGE

  float* Pb = P + (size_t)ks * M * N;
  int crow = (lane >> 4) * 4, ccol = lane & 15;
#pragma unroll
  for (int mi = 0; mi < 4; mi++) {
    int rb = m0 + wr * 64 + mi * 16 + crow;
#pragma unroll
    for (int ni = 0; ni < 4; ni++) {
      int col = n0 + wc * 64 + ni * 16 + ccol;
#pragma unroll
      for (int r = 0; r < 4; r++) {
        int row = rb + r;
        if (row < M) Pb[(size_t)row * N + col] = acc[mi][ni][r];
      }
    }
  }
}

// ====== fused: split-K reduce + bias + BN stats  -> grid sync ->  BN normalize+relu->bf16 ======
// grid MUST be 256 (1 block/CU, co-resident). Pass2 touches only pass1's own rows (L2-coherent).
template<int KS>
__global__ __launch_bounds__(256) void reduce_bn_fused(
    const float* __restrict__ P, const float* __restrict__ bias,
    float* __restrict__ X, float* __restrict__ stats, int* __restrict__ cnt,
    const float* __restrict__ g, const float* __restrict__ bta,
    __hip_bfloat16* __restrict__ obf, int M) {
  __shared__ float sscale[FDIM], sshift[FDIM];
  int t = threadIdx.x, b = blockIdx.x;
  int col = t * 4;
  f32x4 bv = *(const f32x4*)(bias + col);
  f32x4 s = {0, 0, 0, 0}, q = {0, 0, 0, 0};
  for (int r = b; r < M; r += 256) {
    size_t base = (size_t)r * FDIM + col;
    f32x4 vs[KS];
#pragma unroll
    for (int c = 0; c < KS; c++)
      vs[c] = *(const f32x4*)(P + (size_t)c * MN + base);
    f32x4 v = bv;
#pragma unroll
    for (int c = 0; c < KS; c++) v = v + vs[c];
    *(f32x4*)(X + base) = v;
    s = s + v;
    q = q + v * v;
  }
#pragma unroll
  for (int j = 0; j < 4; j++) {
    atomicAdd(&stats[col + j], s[j]);
    atomicAdd(&stats[FDIM + col + j], q[j]);
  }

  grid_sync(cnt, 256);

  float inv_m = 1.0f / (float)M;
  for (int i = t; i < FDIM; i += 256) {      // fresh device-scope reads of stats
    float sm = atomicAdd(&stats[i], 0.0f);
    float sq = atomicAdd(&stats[FDIM + i], 0.0f);
    float mean = sm * inv_m;
    float var = sq * inv_m - mean * mean;
    float sc = rsqrtf(var + EPSBN) * g[i];
    sscale[i] = sc;
    sshift[i] = bta[i] - mean * sc;
  }
  __syncthreads();

  f32x4 scv = *(const f32x4*)(sscale + col);
  f32x4 shv = *(const f32x4*)(sshift + col);
  for (int r = b; r < M; r += 256) {         // own rows: written by this block in pass1
    size_t base = (size_t)r * FDIM + col;
    f32x4 x = *(const f32x4*)(X + base);
    bf16x4 o;
#pragma unroll
    for (int j = 0; j < 4; j++) {
      __hip_bfloat16 hh = __float2bfloat16(fmaxf(x[j] * scv[j] + shv[j], 0.0f));
      o[j] = *reinterpret_cast<short*>(&hh);
    }
    *(bf16x4*)((short*)obf + base) = o;
  }
}

// ====== fused: split-K reduce + bias + BN stats -> grid sync -> BN2+heads (LDS-staged) ======
// grid MUST be 256. Pass2 rows = pass1 rows of the same block (L2-coherent).
template<int KS>
__global__ __launch_bounds__(256) void reduce_heads_fused(
    const float* __restrict__ P, const float* __restrict__ bias,
    float* __restrict__ X, float* __restrict__ stats, int* __restrict__ cnt,
    const float* __restrict__ gg, const float* __restrict__ bb,
    const float* __restrict__ cls_w, const float* __restrict__ cls_b,
    const float* __restrict__ dw, const float* __restrict__ db,
    float* __restrict__ out, int M) {
  __shared__ float sscale[FDIM], sshift[FDIM];   // 8 KB
  __shared__ float clsT[2][FDIM];                // 8 KB
  __shared__ float dwT[8][FDIM];                 // 32 KB
  int t = threadIdx.x, b = blockIdx.x;
  int col = t * 4;
  f32x4 bv = *(const f32x4*)(bias + col);
  f32x4 s = {0, 0, 0, 0}, q = {0, 0, 0, 0};
  for (int r = b; r < M; r += 256) {
    size_t base = (size_t)r * FDIM + col;
    f32x4 vs[KS];
#pragma unroll
    for (int c = 0; c < KS; c++)
      vs[c] = *(const f32x4*)(P + (size_t)c * MN + base);
    f32x4 v = bv;
#pragma unroll
    for (int c = 0; c < KS; c++) v = v + vs[c];
    *(f32x4*)(X + base) = v;
    s = s + v;
    q = q + v * v;
  }
#pragma unroll
  for (int j = 0; j < 4; j++) {
    atomicAdd(&stats[col + j], s[j]);
    atomicAdd(&stats[FDIM + col + j], q[j]);
  }

  grid_sync(cnt, 256);

  float inv_m = 1.0f / (float)M;
  for (int i = t; i < FDIM; i += 256) {
    float sm = atomicAdd(&stats[i], 0.0f);
    float sq = atomicAdd(&stats[FDIM + i], 0.0f);
    float mean = sm * inv_m;
    float var = sq * inv_m - mean * mean;
    float sc = rsqrtf(var + EPSBN) * gg[i];
    sscale[i] = sc;
    sshift[i] = bb[i] - mean * sc;
    clsT[0][i] = cls_w[i * 2];
    clsT[1][i] = cls_w[i * 2 + 1];
#pragma unroll
    for (int j = 0; j < 8; j++) dwT[j][i] = dw[i * 8 + j];
  }
  __syncthreads();

  int lane = t & 63, wv = t >> 6;
  for (int k = wv; k < 8; k += 4) {
    int row = b + (k << 8);                    // own rows (pass1-written by this block)
    if (row >= M) break;
    const float* xrow = X + (size_t)row * FDIM;
    float a[10];
#pragma unroll
    for (int j = 0; j < 10; j++) a[j] = 0.0f;
    for (int kk = lane; kk < FDIM; kk += 64) {
      float v = fmaxf(xrow[kk] * sscale[kk] + sshift[kk], 0.0f);
      a[0] += v * clsT[0][kk];
      a[1] += v * clsT[1][kk];
#pragma unroll
      for (int j = 0; j < 8; j++) a[2 + j] += v * dwT[j][kk];
    }
#pragma unroll
    for (int j = 0; j < 10; j++)
      for (int o = 32; o > 0; o >>= 1) a[j] += __shfl_xor(a[j], o, 64);
    if (lane == 0) {
      float l0 = a[0] + cls_b[0], l1 = a[1] + cls_b[1];
      out[row * 2 + 0] = l0;
      out[row * 2 + 1] = l1;
      float mx = fmaxf(l0, l1);
      float e0 = expf(l0 - mx), e1 = expf(l1 - mx);
      float inv = 1.0f / (e0 + e1);
      out[4000 + row * 2 + 0] = e0 * inv;
      out[4000 + row * 2 + 1] = e1 * inv;
#pragma unroll
      for (int j = 0; j < 8; j++) out[8000 + row * 8 + j] = a[2 + j] + db[j];
    }
  }
}

extern "C" void kernel_launch(void* const* d_in, const int* in_sizes, int n_in,
                              void* d_out, int out_size, void* d_ws, size_t ws_size,
                              hipStream_t stream) {
  const float* rois    = (const float*)d_in[0];
  const float* p2      = (const float*)d_in[1];
  const float* p3      = (const float*)d_in[2];
  const float* p4      = (const float*)d_in[3];
  const float* p5      = (const float*)d_in[4];
  const float* conv1_w = (const float*)d_in[5];
  const float* conv1_b = (const float*)d_in[6];
  const float* bn1_g   = (const float*)d_in[7];
  const float* bn1_b   = (const float*)d_in[8];
  const float* conv2_w = (const float*)d_in[9];
  const float* conv2_b = (const float*)d_in[10];
  const float* bn2_g   = (const float*)d_in[11];
  const float* bn2_b   = (const float*)d_in[12];
  const float* cls_w   = (const float*)d_in[13];
  const float* cls_b   = (const float*)d_in[14];
  const float* delta_w = (const float*)d_in[15];
  const float* delta_b = (const float*)d_in[16];
  float* out = (float*)d_out;

  char* ws = (char*)d_ws;
  size_t off = 0;
  __hip_bfloat16* pooled = (__hip_bfloat16*)(ws + off); off += (size_t)M_ROWS * K1 * 2;   // 50,176,000
  __hip_bfloat16* w1t    = (__hip_bfloat16*)(ws + off); off += (size_t)K1 * FDIM * 2;     // 25,690,112
  __hip_bfloat16* w2t    = (__hip_bfloat16*)(ws + off); off += (size_t)FDIM * FDIM * 2;   //  2,097,152
  float* stats1          = (float*)(ws + off);          off += 2 * FDIM * 4;
  float* stats2          = (float*)(ws + off);          off += 2 * FDIM * 4;              // stats1+2048
  int*   cnts            = (int*)(ws + off);            off += 256;                       // at stats1+4096
  char*  Preg            = ws + off;                    off += (size_t)4 * MN * 4;        // 32,768,000
  // temporal aliasing:
  //  GEMM1 partials = Preg S0..S3 ; fusedA -> x1 = S0, x1n in pooled region
  //  GEMM2 partials = Preg S0..S3 (x1 dead) ; fusedB -> x2 = S0
  float* part1        = (float*)Preg;
  float* x1           = (float*)Preg;
  __hip_bfloat16* x1n = (__hip_bfloat16*)pooled;
  float* part2        = (float*)Preg;
  float* x2           = (float*)Preg;

  // prep: zero-stats+counters | roi-align | transpose w1 | transpose w2 (concurrent)
  prep_kernel<<<1 + M_ROWS + 3136 + 256, 256, 0, stream>>>(
      rois, p2, p3, p4, p5, pooled, conv1_w, w1t, conv2_w, w2t, stats1);

  // GEMM1: 8-wave pipelined, split-K=4 (Kc=3136), grid 16*4*4 = 256
  gemm8w<4><<<256, 512, 0, stream>>>((const short*)pooled, (const short*)w1t, part1,
                                     M_ROWS, FDIM, K1);
  // fused reduce1 + BN1 normalize -> x1n (bf16, in pooled region)
  reduce_bn_fused<4><<<256, 256, 0, stream>>>(part1, conv1_b, x1, stats1, &cnts[0],
                                              bn1_g, bn1_b, x1n, M_ROWS);

  // GEMM2: same pipelined kernel, split-K=4 (Kc=256), grid 256
  gemm8w<4><<<256, 512, 0, stream>>>((const short*)x1n, (const short*)w2t, part2,
                                     M_ROWS, FDIM, FDIM);
  // fused reduce2 + BN2 + heads
  reduce_heads_fused<4><<<256, 256, 0, stream>>>(part2, conv2_b, x2, stats2, &cnts[1],
                                                 bn2_g, bn2_b, cls_w, cls_b,
                                                 delta_w, delta_b, out, M_ROWS);

  (void)in_sizes; (void)n_in; (void)out_size; (void)ws_size;
}

// Round 14
// 219.145 us; speedup vs baseline: 1.1920x; 1.1920x over previous
//
#include <hip/hip_runtime.h>
#include <hip/hip_bf16.h>

#define NB     2
#define NROI   1000
#define CIN    256
#define FDIM   1024
#define M_ROWS 2000          // NB*NROI
#define K1     12544         // 7*7*256
#define EPSBN  1e-3f
#define MN     (M_ROWS * FDIM)

typedef short bf16x8 __attribute__((ext_vector_type(8)));
typedef short bf16x4 __attribute__((ext_vector_type(4)));
typedef float f32x4  __attribute__((ext_vector_type(4)));

__device__ __forceinline__ void gld_lds16(const void* g, void* l) {
  __builtin_amdgcn_global_load_lds((const __attribute__((address_space(1))) char*)g,
                                   (__attribute__((address_space(3))) char*)l, 16, 0, 0);
}

// ================= prep: zero-stats | roi-align | transpose1 | transpose2 =================
// logical grid: [0]=zero, [1,2001)=roi, [2001,5137)=w1 tiles, [5137,5393)=w2 tiles
// physical->logical remap interleaves latency-bound roi with BW-bound transpose:
//   idx<5392: even -> idx/2 (zero+roi+early w1), odd -> 2696+idx/2 (late w1+w2); 5392 -> itself.
__global__ __launch_bounds__(256) void prep_kernel(
    const float* __restrict__ rois,
    const float* __restrict__ p2, const float* __restrict__ p3,
    const float* __restrict__ p4, const float* __restrict__ p5,
    __hip_bfloat16* __restrict__ pooled,
    const float* __restrict__ conv1_w, __hip_bfloat16* __restrict__ w1t,
    const float* __restrict__ conv2_w, __hip_bfloat16* __restrict__ w2t,
    float* __restrict__ stats) {
  __shared__ float tt[64][65];
  int pidx = blockIdx.x;
  int idx = (pidx < 5392) ? ((pidx & 1) ? 2696 + (pidx >> 1) : (pidx >> 1)) : pidx;
  int t = threadIdx.x;

  if (idx == 0) {                      // zero stats1+stats2 (4096 floats)
#pragma unroll
    for (int i = 0; i < 4; i++)
      ((f32x4*)stats)[t + i * 256] = f32x4{0, 0, 0, 0};
    return;
  }

  if (idx < 1 + M_ROWS) {              // ---- ROI align ----
    int rn = idx - 1;
    int b = rn / NROI;

    const float* roi = rois + (size_t)rn * 4;
    float y1 = roi[0], x1 = roi[1], y2 = roi[2], x2 = roi[3];
    float h = y2 - y1, w = x2 - x1;
    float lvl = log2f(fmaxf(sqrtf(h * w), 1e-9f) * 4.0f);   // scale 0.25 -> *4 exact
    int li = 4 + (int)rintf(lvl);
    li = min(max(li, 2), 5) - 2;

    const float* fm; int H;
    switch (li) {
      case 0:  fm = p2; H = 256; break;
      case 1:  fm = p3; H = 128; break;
      case 2:  fm = p4; H = 64;  break;
      default: fm = p5; H = 32;  break;
    }
    int W = H;
    const float* fb = fm + (size_t)b * H * W * CIN;

    int lane = t & 63, wv = t >> 6;
    int c4 = lane * 4;

    for (int pos = wv; pos < 49; pos += 4) {
      int py = pos / 7, px = pos - py * 7;
      float fy = (float)py / 6.0f, fx = (float)px / 6.0f;
      float ys = (y1 + (y2 - y1) * fy) * (float)(H - 1);
      float xs = (x1 + (x2 - x1) * fx) * (float)(W - 1);
      float y0f = floorf(ys), x0f = floorf(xs);
      float wy = ys - y0f, wx = xs - x0f;
      int y0 = min(max((int)y0f, 0), H - 1);
      int x0 = min(max((int)x0f, 0), W - 1);
      int y1i = min(y0 + 1, H - 1);
      int x1i = min(x0 + 1, W - 1);

      f32x4 v00 = *(const f32x4*)(fb + ((size_t)y0 * W + x0) * CIN + c4);
      f32x4 v01 = *(const f32x4*)(fb + ((size_t)y0 * W + x1i) * CIN + c4);
      f32x4 v10 = *(const f32x4*)(fb + ((size_t)y1i * W + x0) * CIN + c4);
      f32x4 v11 = *(const f32x4*)(fb + ((size_t)y1i * W + x1i) * CIN + c4);

      f32x4 top = v00 + (v01 - v00) * wx;
      f32x4 bot = v10 + (v11 - v10) * wx;
      f32x4 val = top + (bot - top) * wy;

      bf16x4 o;
#pragma unroll
      for (int j = 0; j < 4; j++) {
        __hip_bfloat16 hh = __float2bfloat16(val[j]);
        o[j] = *reinterpret_cast<short*>(&hh);
      }
      *(bf16x4*)((short*)pooled + ((size_t)rn * 49 + pos) * CIN + c4) = o;
    }
    return;
  }

  // ---- transpose 64x64 tile: W[K][N] -> WT[N][K] bf16 ----
  const float* W; short* WT; int K, N, bx, by;
  if (idx < 1 + M_ROWS + 3136) {
    int wk = idx - (1 + M_ROWS);
    W = conv1_w; WT = (short*)w1t; K = K1; N = FDIM;
    bx = wk % 196; by = wk / 196;
  } else {
    int wk = idx - (1 + M_ROWS + 3136);
    W = conv2_w; WT = (short*)w2t; K = FDIM; N = FDIM;
    bx = wk % 16; by = wk / 16;
  }
  int k0 = bx * 64, n0 = by * 64;
  int r = t >> 2, c = t & 3;
#pragma unroll
  for (int i = 0; i < 4; i++) {
    int cg = c * 4 + i;                 // float4 column group 0..15
    f32x4 v = *(const f32x4*)(W + (size_t)(k0 + r) * N + n0 + cg * 4);
#pragma unroll
    for (int j = 0; j < 4; j++) tt[cg * 4 + j][r] = v[j];
  }
  __syncthreads();
  int n = t >> 2, g = t & 3;
#pragma unroll
  for (int i = 0; i < 2; i++) {
    int seg = g * 2 + i;                // 8 segments of 8 bf16
    bf16x8 o;
#pragma unroll
    for (int j = 0; j < 8; j++) {
      __hip_bfloat16 hh = __float2bfloat16(tt[n][seg * 8 + j]);
      o[j] = *reinterpret_cast<short*>(&hh);
    }
    *(bf16x8*)(WT + (size_t)(n0 + n) * K + k0 + seg * 8) = o;
  }
}

// ================= 8-wave deep-pipelined GEMM (GEMM1 + GEMM2) =================
// BM=128, BN=256, BK=64 (2 kh-halves of 32). 512 thr = 8 waves (2M x 4N),
// each wave 64x64 out (4x4 16x16x32 frags). Split-K: P[ks][M][N] f32.
// LDS: A[buf][kh][128][32], B[buf][kh][256][32], slot-swizzled (g^(row&3)).
// Pipeline: 3 half-stages in flight (9 loads), vmcnt(6) boundaries.
template<int KSLICES>
__global__ __launch_bounds__(512) void gemm8w(const short* __restrict__ A,
                                              const short* __restrict__ BT,
                                              float* __restrict__ P,
                                              int M, int N, int K) {
  __shared__ short As[4 * 128 * 32];   // (buf*2+kh)*4096
  __shared__ short Bs[4 * 256 * 32];   // (buf*2+kh)*8192

  int nwg = gridDim.x;                 // divisible by 8
  int bid = blockIdx.x;
  int cpx = nwg >> 3;
  int wg = (bid & 7) * cpx + (bid >> 3);

  int MT = (M + 127) >> 7;
  int NTn = N >> 8;
  int tiles = MT * NTn;
  int ks = wg / tiles;
  int rem = wg % tiles;
  int tm = rem % MT, tn = rem / MT;
  int m0 = tm * 128, n0 = tn * 256;
  int Kc = K / KSLICES;
  int NT = Kc >> 6;                    // K-tiles of 64
  size_t kb = (size_t)ks * Kc;

  int tid = threadIdx.x;
  int lane = tid & 63, wid = tid >> 6;
  int wr = wid >> 2, wc = wid & 3;

  // staging sources (pre-swizzled): granule (row, slot) holds logical g = slot^(row&3)
  int srow = tid >> 2;
  int g = (tid & 3) ^ (srow & 3);
  const short* Agb  = A  + (size_t)min(m0 + srow, M - 1) * K + kb + g * 8;
  const short* Bgb0 = BT + (size_t)(n0 + srow) * K + kb + g * 8;
  const short* Bgb1 = Bgb0 + (size_t)128 * K;
  int aoff  = wid * 512;
  int boff0 = wid * 512;
  int boff1 = 4096 + wid * 512;

  // fragment read bases (swizzled): addr = row*32 + ((lane>>4)^(lane&3))*8
  int lr = lane & 15;
  int slotoff = ((lane >> 4) ^ (lane & 3)) * 8;
  const short* Ard = As + (wr * 64 + lr) * 32 + slotoff;
  const short* Brd = Bs + (wc * 64 + lr) * 32 + slotoff;

  f32x4 acc[4][4] = {};

#define STAGE(s) do {                                                        \
    int ts_ = (s) >> 1, kh_ = (s) & 1, b_ = ts_ & 1;                         \
    int ko_ = ts_ * 64 + kh_ * 32;                                           \
    short* Ad_ = (short*)As + (b_ * 2 + kh_) * 4096 + aoff;                  \
    short* Bd_ = (short*)Bs + (b_ * 2 + kh_) * 8192;                         \
    gld_lds16(Agb + ko_, Ad_);                                               \
    gld_lds16(Bgb0 + ko_, Bd_ + boff0);                                      \
    gld_lds16(Bgb1 + ko_, Bd_ + boff1);                                      \
  } while (0)

  STAGE(0); STAGE(1); STAGE(2);

  for (int t = 0; t < NT; ++t) {
    int b = t & 1;
#pragma unroll
    for (int kh = 0; kh < 2; ++kh) {
      __builtin_amdgcn_sched_barrier(0);
      if (t < NT - 1)      asm volatile("s_waitcnt vmcnt(6)" ::: "memory");
      else if (kh == 0)    asm volatile("s_waitcnt vmcnt(3)" ::: "memory");
      else                 asm volatile("s_waitcnt vmcnt(0)" ::: "memory");
      __builtin_amdgcn_s_barrier();
      __builtin_amdgcn_sched_barrier(0);

      const short* Ab = Ard + (b * 2 + kh) * 4096;
      const short* Bb = Brd + (b * 2 + kh) * 8192;
      bf16x8 af[4], bf_[4];
#pragma unroll
      for (int mi = 0; mi < 4; mi++) af[mi] = *(const bf16x8*)(Ab + mi * 512);
#pragma unroll
      for (int ni = 0; ni < 4; ni++) bf_[ni] = *(const bf16x8*)(Bb + ni * 512);

      if (kh == 0) { if (t + 1 < NT) STAGE(2 * t + 3); }
      else         { if (t + 2 < NT) STAGE(2 * t + 4); }

      __builtin_amdgcn_sched_barrier(0);
      asm volatile("s_waitcnt lgkmcnt(0)" ::: "memory");
      __builtin_amdgcn_sched_barrier(0);
      __builtin_amdgcn_s_setprio(1);
#pragma unroll
      for (int mi = 0; mi < 4; mi++)
#pragma unroll
        for (int ni = 0; ni < 4; ni++)
          acc[mi][ni] = __builtin_amdgcn_mfma_f32_16x16x32_bf16(af[mi], bf_[ni], acc[mi][ni], 0, 0, 0);
      __builtin_amdgcn_s_setprio(0);
    }
  }
#undef STAGE

  float* Pb = P + (size_t)ks * M * N;
  int crow = (lane >> 4) * 4, ccol = lane & 15;
#pragma unroll
  for (int mi = 0; mi < 4; mi++) {
    int rb = m0 + wr * 64 + mi * 16 + crow;
#pragma unroll
    for (int ni = 0; ni < 4; ni++) {
      int col = n0 + wc * 64 + ni * 16 + ccol;
#pragma unroll
      for (int r = 0; r < 4; r++) {
        int row = rb + r;
        if (row < M) Pb[(size_t)row * N + col] = acc[mi][ni][r];
      }
    }
  }
}

// ------- fused split-K reduce + bias + BN stats; templated KS (unrolled ILP), grid 256 -------
template<int KS>
__global__ void reduce_bias_stats(const float* __restrict__ P, const float* __restrict__ bias,
                                  float* __restrict__ X, float* __restrict__ stats, int M) {
  int t = threadIdx.x;                 // 256 threads, 4 consecutive features
  int col = t * 4;
  f32x4 bv = *(const f32x4*)(bias + col);
  f32x4 s = {0, 0, 0, 0}, q = {0, 0, 0, 0};
  for (int r = blockIdx.x; r < M; r += gridDim.x) {
    size_t base = (size_t)r * FDIM + col;
    f32x4 vs[KS];
#pragma unroll
    for (int c = 0; c < KS; c++)                       // independent loads, all in flight
      vs[c] = *(const f32x4*)(P + (size_t)c * MN + base);
    f32x4 v = bv;
#pragma unroll
    for (int c = 0; c < KS; c++) v = v + vs[c];
    *(f32x4*)(X + base) = v;
    s = s + v;
    q = q + v * v;
  }
#pragma unroll
  for (int j = 0; j < 4; j++) {
    atomicAdd(&stats[col + j], s[j]);
    atomicAdd(&stats[FDIM + col + j], q[j]);
  }
}

// ---------------- BN normalize + relu -> bf16 (vectorized x4) ----------------
__global__ void bn_norm_relu_bf16(const float* __restrict__ X, const float* __restrict__ stats,
                                  const float* __restrict__ g, const float* __restrict__ bta,
                                  __hip_bfloat16* __restrict__ obf, int M) {
  int i4 = blockIdx.x * blockDim.x + threadIdx.x;
  if (i4 * 4 >= M * FDIM) return;
  int f = (i4 * 4) & (FDIM - 1);
  f32x4 x  = *(const f32x4*)(X + (size_t)i4 * 4);
  f32x4 sm = *(const f32x4*)(stats + f);
  f32x4 sq = *(const f32x4*)(stats + FDIM + f);
  f32x4 gv = *(const f32x4*)(g + f);
  f32x4 bv = *(const f32x4*)(bta + f);
  float inv_m = 1.0f / (float)M;
  bf16x4 o;
#pragma unroll
  for (int j = 0; j < 4; j++) {
    float mean = sm[j] * inv_m;
    float var = sq[j] * inv_m - mean * mean;
    float xn = (x[j] - mean) * rsqrtf(var + EPSBN) * gv[j] + bv[j];
    __hip_bfloat16 hh = __float2bfloat16(fmaxf(xn, 0.0f));
    o[j] = *reinterpret_cast<short*>(&hh);
  }
  *(bf16x4*)((short*)obf + (size_t)i4 * 4) = o;
}

// -------- heads with BN2 normalize+relu fused in: logits, softmax, deltas --------
__global__ void heads_bn(const float* __restrict__ X2, const float* __restrict__ stats,
                         const float* __restrict__ gg, const float* __restrict__ bb,
                         const float* __restrict__ cls_w, const float* __restrict__ cls_b,
                         const float* __restrict__ dw, const float* __restrict__ db,
                         float* __restrict__ out) {
  int row = blockIdx.x * 4 + (threadIdx.x >> 6);
  int lane = threadIdx.x & 63;
  if (row >= M_ROWS) return;
  const float* xrow = X2 + (size_t)row * FDIM;
  float inv_m = 1.0f / (float)M_ROWS;
  float a[10];
#pragma unroll
  for (int j = 0; j < 10; j++) a[j] = 0.0f;
  for (int k = lane; k < FDIM; k += 64) {
    float mean = stats[k] * inv_m;
    float var = stats[FDIM + k] * inv_m - mean * mean;
    float v = fmaxf((xrow[k] - mean) * rsqrtf(var + EPSBN) * gg[k] + bb[k], 0.0f);
    a[0] += v * cls_w[k * 2 + 0];
    a[1] += v * cls_w[k * 2 + 1];
#pragma unroll
    for (int j = 0; j < 8; j++) a[2 + j] += v * dw[k * 8 + j];
  }
#pragma unroll
  for (int j = 0; j < 10; j++)
    for (int o = 32; o > 0; o >>= 1) a[j] += __shfl_xor(a[j], o, 64);
  if (lane == 0) {
    float l0 = a[0] + cls_b[0], l1 = a[1] + cls_b[1];
    out[row * 2 + 0] = l0;
    out[row * 2 + 1] = l1;
    float mx = fmaxf(l0, l1);
    float e0 = expf(l0 - mx), e1 = expf(l1 - mx);
    float inv = 1.0f / (e0 + e1);
    out[4000 + row * 2 + 0] = e0 * inv;
    out[4000 + row * 2 + 1] = e1 * inv;
#pragma unroll
    for (int j = 0; j < 8; j++) out[8000 + row * 8 + j] = a[2 + j] + db[j];
  }
}

extern "C" void kernel_launch(void* const* d_in, const int* in_sizes, int n_in,
                              void* d_out, int out_size, void* d_ws, size_t ws_size,
                              hipStream_t stream) {
  const float* rois    = (const float*)d_in[0];
  const float* p2      = (const float*)d_in[1];
  const float* p3      = (const float*)d_in[2];
  const float* p4      = (const float*)d_in[3];
  const float* p5      = (const float*)d_in[4];
  const float* conv1_w = (const float*)d_in[5];
  const float* conv1_b = (const float*)d_in[6];
  const float* bn1_g   = (const float*)d_in[7];
  const float* bn1_b   = (const float*)d_in[8];
  const float* conv2_w = (const float*)d_in[9];
  const float* conv2_b = (const float*)d_in[10];
  const float* bn2_g   = (const float*)d_in[11];
  const float* bn2_b   = (const float*)d_in[12];
  const float* cls_w   = (const float*)d_in[13];
  const float* cls_b   = (const float*)d_in[14];
  const float* delta_w = (const float*)d_in[15];
  const float* delta_b = (const float*)d_in[16];
  float* out = (float*)d_out;

  char* ws = (char*)d_ws;
  size_t off = 0;
  __hip_bfloat16* pooled = (__hip_bfloat16*)(ws + off); off += (size_t)M_ROWS * K1 * 2;   // 50,176,000
  __hip_bfloat16* w1t    = (__hip_bfloat16*)(ws + off); off += (size_t)K1 * FDIM * 2;     // 25,690,112
  __hip_bfloat16* w2t    = (__hip_bfloat16*)(ws + off); off += (size_t)FDIM * FDIM * 2;   //  2,097,152
  float* stats1          = (float*)(ws + off);          off += 2 * FDIM * 4;
  float* stats2          = (float*)(ws + off);          off += 2 * FDIM * 4;
  char*  Preg            = ws + off;                    off += (size_t)4 * MN * 4;        // 32,768,000
  // temporal aliasing:
  //  GEMM1 partials = Preg S0..S3 ; reduce1 -> x1 = S0
  //  bn_norm -> x1n in pooled region (dead after GEMM1)
  //  GEMM2 partials = Preg S0..S3 (x1 dead) ; reduce2 -> x2 = S0
  float* part1        = (float*)Preg;
  float* x1           = (float*)Preg;
  __hip_bfloat16* x1n = (__hip_bfloat16*)pooled;
  float* part2        = (float*)Preg;
  float* x2           = (float*)Preg;

  // prep: zero-stats | roi-align | transpose w1 | transpose w2 (interleaved dispatch)
  prep_kernel<<<1 + M_ROWS + 3136 + 256, 256, 0, stream>>>(
      rois, p2, p3, p4, p5, pooled, conv1_w, w1t, conv2_w, w2t, stats1);

  // GEMM1: 8-wave pipelined, split-K=4 (Kc=3136), grid 16*4*4 = 256
  gemm8w<4><<<256, 512, 0, stream>>>((const short*)pooled, (const short*)w1t, part1,
                                     M_ROWS, FDIM, K1);
  reduce_bias_stats<4><<<256, 256, 0, stream>>>(part1, conv1_b, x1, stats1, M_ROWS);

  bn_norm_relu_bf16<<<MN / 1024, 256, 0, stream>>>(x1, stats1, bn1_g, bn1_b, x1n, M_ROWS);

  // GEMM2: same pipelined kernel, split-K=4 (Kc=256), grid 256
  gemm8w<4><<<256, 512, 0, stream>>>((const short*)x1n, (const short*)w2t, part2,
                                     M_ROWS, FDIM, FDIM);
  reduce_bias_stats<4><<<256, 256, 0, stream>>>(part2, conv2_b, x2, stats2, M_ROWS);

  heads_bn<<<(M_ROWS + 3) / 4, 256, 0, stream>>>(x2, stats2, bn2_g, bn2_b,
                                                 cls_w, cls_b, delta_w, delta_b, out);

  (void)in_sizes; (void)n_in; (void)out_size; (void)ws_size;
}

// Round 15
// 205.849 us; speedup vs baseline: 1.2690x; 1.0646x over previous
//
#include <hip/hip_runtime.h>
#include <hip/hip_bf16.h>

#define NB     2
#define NROI   1000
#define CIN    256
#define FDIM   1024
#define M_ROWS 2000          // NB*NROI
#define K1     12544         // 7*7*256
#define EPSBN  1e-3f
#define MN     (M_ROWS * FDIM)

typedef short bf16x8 __attribute__((ext_vector_type(8)));
typedef short bf16x4 __attribute__((ext_vector_type(4)));
typedef float f32x4  __attribute__((ext_vector_type(4)));

__device__ __forceinline__ void gld_lds16(const void* g, void* l) {
  __builtin_amdgcn_global_load_lds((const __attribute__((address_space(1))) char*)g,
                                   (__attribute__((address_space(3))) char*)l, 16, 0, 0);
}

// ================= prep: zero-stats | roi-align | transpose1 | transpose2 =================
// grid: [0]=zero, [1,2001)=roi, [2001,5137)=w1 tiles, [5137,5393)=w2 tiles
__global__ __launch_bounds__(256) void prep_kernel(
    const float* __restrict__ rois,
    const float* __restrict__ p2, const float* __restrict__ p3,
    const float* __restrict__ p4, const float* __restrict__ p5,
    __hip_bfloat16* __restrict__ pooled,
    const float* __restrict__ conv1_w, __hip_bfloat16* __restrict__ w1t,
    const float* __restrict__ conv2_w, __hip_bfloat16* __restrict__ w2t,
    float* __restrict__ stats) {
  __shared__ float tt[64][65];
  int idx = blockIdx.x;
  int t = threadIdx.x;

  if (idx == 0) {                      // zero stats1+stats2 (4096 floats)
#pragma unroll
    for (int i = 0; i < 4; i++)
      ((f32x4*)stats)[t + i * 256] = f32x4{0, 0, 0, 0};
    return;
  }

  if (idx < 1 + M_ROWS) {              // ---- ROI align ----
    int rn = idx - 1;
    int b = rn / NROI;

    const float* roi = rois + (size_t)rn * 4;
    float y1 = roi[0], x1 = roi[1], y2 = roi[2], x2 = roi[3];
    float h = y2 - y1, w = x2 - x1;
    float lvl = log2f(fmaxf(sqrtf(h * w), 1e-9f) * 4.0f);   // scale 0.25 -> *4 exact
    int li = 4 + (int)rintf(lvl);
    li = min(max(li, 2), 5) - 2;

    const float* fm; int H;
    switch (li) {
      case 0:  fm = p2; H = 256; break;
      case 1:  fm = p3; H = 128; break;
      case 2:  fm = p4; H = 64;  break;
      default: fm = p5; H = 32;  break;
    }
    int W = H;
    const float* fb = fm + (size_t)b * H * W * CIN;

    int lane = t & 63, wv = t >> 6;
    int c4 = lane * 4;

    for (int pos = wv; pos < 49; pos += 4) {
      int py = pos / 7, px = pos - py * 7;
      float fy = (float)py / 6.0f, fx = (float)px / 6.0f;
      float ys = (y1 + (y2 - y1) * fy) * (float)(H - 1);
      float xs = (x1 + (x2 - x1) * fx) * (float)(W - 1);
      float y0f = floorf(ys), x0f = floorf(xs);
      float wy = ys - y0f, wx = xs - x0f;
      int y0 = min(max((int)y0f, 0), H - 1);
      int x0 = min(max((int)x0f, 0), W - 1);
      int y1i = min(y0 + 1, H - 1);
      int x1i = min(x0 + 1, W - 1);

      f32x4 v00 = *(const f32x4*)(fb + ((size_t)y0 * W + x0) * CIN + c4);
      f32x4 v01 = *(const f32x4*)(fb + ((size_t)y0 * W + x1i) * CIN + c4);
      f32x4 v10 = *(const f32x4*)(fb + ((size_t)y1i * W + x0) * CIN + c4);
      f32x4 v11 = *(const f32x4*)(fb + ((size_t)y1i * W + x1i) * CIN + c4);

      f32x4 top = v00 + (v01 - v00) * wx;
      f32x4 bot = v10 + (v11 - v10) * wx;
      f32x4 val = top + (bot - top) * wy;

      bf16x4 o;
#pragma unroll
      for (int j = 0; j < 4; j++) {
        __hip_bfloat16 hh = __float2bfloat16(val[j]);
        o[j] = *reinterpret_cast<short*>(&hh);
      }
      *(bf16x4*)((short*)pooled + ((size_t)rn * 49 + pos) * CIN + c4) = o;
    }
    return;
  }

  // ---- transpose 64x64 tile: W[K][N] -> WT[N][K] bf16 ----
  const float* W; short* WT; int K, N, bx, by;
  if (idx < 1 + M_ROWS + 3136) {
    int wk = idx - (1 + M_ROWS);
    W = conv1_w; WT = (short*)w1t; K = K1; N = FDIM;
    bx = wk % 196; by = wk / 196;
  } else {
    int wk = idx - (1 + M_ROWS + 3136);
    W = conv2_w; WT = (short*)w2t; K = FDIM; N = FDIM;
    bx = wk % 16; by = wk / 16;
  }
  int k0 = bx * 64, n0 = by * 64;
  int r = t >> 2, c = t & 3;
#pragma unroll
  for (int i = 0; i < 4; i++) {
    int cg = c * 4 + i;                 // float4 column group 0..15
    f32x4 v = *(const f32x4*)(W + (size_t)(k0 + r) * N + n0 + cg * 4);
#pragma unroll
    for (int j = 0; j < 4; j++) tt[cg * 4 + j][r] = v[j];
  }
  __syncthreads();
  int n = t >> 2, g = t & 3;
#pragma unroll
  for (int i = 0; i < 2; i++) {
    int seg = g * 2 + i;                // 8 segments of 8 bf16
    bf16x8 o;
#pragma unroll
    for (int j = 0; j < 8; j++) {
      __hip_bfloat16 hh = __float2bfloat16(tt[n][seg * 8 + j]);
      o[j] = *reinterpret_cast<short*>(&hh);
    }
    *(bf16x8*)(WT + (size_t)(n0 + n) * K + k0 + seg * 8) = o;
  }
}

// ================= 8-wave deep-pipelined GEMM (GEMM1 + GEMM2) =================
// BM=128, BN=256, BK=64 (2 kh-halves of 32). 512 thr = 8 waves (2M x 4N),
// each wave 64x64 out (4x4 16x16x32 frags). Split-K: P[ks][M][N] f32.
// LDS: A[buf][kh][128][32], B[buf][kh][256][32], slot-swizzled (g^(row&3)).
// Pipeline: 3 half-stages in flight (9 loads), vmcnt(6) boundaries.
template<int KSLICES>
__global__ __launch_bounds__(512) void gemm8w(const short* __restrict__ A,
                                              const short* __restrict__ BT,
                                              float* __restrict__ P,
                                              int M, int N, int K) {
  __shared__ short As[4 * 128 * 32];   // (buf*2+kh)*4096
  __shared__ short Bs[4 * 256 * 32];   // (buf*2+kh)*8192

  int nwg = gridDim.x;                 // divisible by 8
  int bid = blockIdx.x;
  int cpx = nwg >> 3;
  int wg = (bid & 7) * cpx + (bid >> 3);

  int MT = (M + 127) >> 7;
  int NTn = N >> 8;
  int tiles = MT * NTn;
  int ks = wg / tiles;
  int rem = wg % tiles;
  int tm = rem % MT, tn = rem / MT;
  int m0 = tm * 128, n0 = tn * 256;
  int Kc = K / KSLICES;
  int NT = Kc >> 6;                    // K-tiles of 64
  size_t kb = (size_t)ks * Kc;

  int tid = threadIdx.x;
  int lane = tid & 63, wid = tid >> 6;
  int wr = wid >> 2, wc = wid & 3;

  // staging sources (pre-swizzled): granule (row, slot) holds logical g = slot^(row&3)
  int srow = tid >> 2;
  int g = (tid & 3) ^ (srow & 3);
  const short* Agb  = A  + (size_t)min(m0 + srow, M - 1) * K + kb + g * 8;
  const short* Bgb0 = BT + (size_t)(n0 + srow) * K + kb + g * 8;
  const short* Bgb1 = Bgb0 + (size_t)128 * K;
  int aoff  = wid * 512;
  int boff0 = wid * 512;
  int boff1 = 4096 + wid * 512;

  // fragment read bases (swizzled): addr = row*32 + ((lane>>4)^(lane&3))*8
  int lr = lane & 15;
  int slotoff = ((lane >> 4) ^ (lane & 3)) * 8;
  const short* Ard = As + (wr * 64 + lr) * 32 + slotoff;
  const short* Brd = Bs + (wc * 64 + lr) * 32 + slotoff;

  f32x4 acc[4][4] = {};

#define STAGE(s) do {                                                        \
    int ts_ = (s) >> 1, kh_ = (s) & 1, b_ = ts_ & 1;                         \
    int ko_ = ts_ * 64 + kh_ * 32;                                           \
    short* Ad_ = (short*)As + (b_ * 2 + kh_) * 4096 + aoff;                  \
    short* Bd_ = (short*)Bs + (b_ * 2 + kh_) * 8192;                         \
    gld_lds16(Agb + ko_, Ad_);                                               \
    gld_lds16(Bgb0 + ko_, Bd_ + boff0);                                      \
    gld_lds16(Bgb1 + ko_, Bd_ + boff1);                                      \
  } while (0)

  STAGE(0); STAGE(1); STAGE(2);

  for (int t = 0; t < NT; ++t) {
    int b = t & 1;
#pragma unroll
    for (int kh = 0; kh < 2; ++kh) {
      __builtin_amdgcn_sched_barrier(0);
      if (t < NT - 1)      asm volatile("s_waitcnt vmcnt(6)" ::: "memory");
      else if (kh == 0)    asm volatile("s_waitcnt vmcnt(3)" ::: "memory");
      else                 asm volatile("s_waitcnt vmcnt(0)" ::: "memory");
      __builtin_amdgcn_s_barrier();
      __builtin_amdgcn_sched_barrier(0);

      const short* Ab = Ard + (b * 2 + kh) * 4096;
      const short* Bb = Brd + (b * 2 + kh) * 8192;
      bf16x8 af[4], bf_[4];
#pragma unroll
      for (int mi = 0; mi < 4; mi++) af[mi] = *(const bf16x8*)(Ab + mi * 512);
#pragma unroll
      for (int ni = 0; ni < 4; ni++) bf_[ni] = *(const bf16x8*)(Bb + ni * 512);

      if (kh == 0) { if (t + 1 < NT) STAGE(2 * t + 3); }
      else         { if (t + 2 < NT) STAGE(2 * t + 4); }

      __builtin_amdgcn_sched_barrier(0);
      asm volatile("s_waitcnt lgkmcnt(0)" ::: "memory");
      __builtin_amdgcn_sched_barrier(0);
      __builtin_amdgcn_s_setprio(1);
#pragma unroll
      for (int mi = 0; mi < 4; mi++)
#pragma unroll
        for (int ni = 0; ni < 4; ni++)
          acc[mi][ni] = __builtin_amdgcn_mfma_f32_16x16x32_bf16(af[mi], bf_[ni], acc[mi][ni], 0, 0, 0);
      __builtin_amdgcn_s_setprio(0);
    }
  }
#undef STAGE

  float* Pb = P + (size_t)ks * M * N;
  int crow = (lane >> 4) * 4, ccol = lane & 15;
#pragma unroll
  for (int mi = 0; mi < 4; mi++) {
    int rb = m0 + wr * 64 + mi * 16 + crow;
#pragma unroll
    for (int ni = 0; ni < 4; ni++) {
      int col = n0 + wc * 64 + ni * 16 + ccol;
#pragma unroll
      for (int r = 0; r < 4; r++) {
        int row = rb + r;
        if (row < M) Pb[(size_t)row * N + col] = acc[mi][ni][r];
      }
    }
  }
}

// ------- fused split-K reduce + bias + BN stats; templated KS (unrolled ILP), grid 256 -------
template<int KS>
__global__ void reduce_bias_stats(const float* __restrict__ P, const float* __restrict__ bias,
                                  float* __restrict__ X, float* __restrict__ stats, int M) {
  int t = threadIdx.x;                 // 256 threads, 4 consecutive features
  int col = t * 4;
  f32x4 bv = *(const f32x4*)(bias + col);
  f32x4 s = {0, 0, 0, 0}, q = {0, 0, 0, 0};
  for (int r = blockIdx.x; r < M; r += gridDim.x) {
    size_t base = (size_t)r * FDIM + col;
    f32x4 vs[KS];
#pragma unroll
    for (int c = 0; c < KS; c++)                       // independent loads, all in flight
      vs[c] = *(const f32x4*)(P + (size_t)c * MN + base);
    f32x4 v = bv;
#pragma unroll
    for (int c = 0; c < KS; c++) v = v + vs[c];
    *(f32x4*)(X + base) = v;
    s = s + v;
    q = q + v * v;
  }
#pragma unroll
  for (int j = 0; j < 4; j++) {
    atomicAdd(&stats[col + j], s[j]);
    atomicAdd(&stats[FDIM + col + j], q[j]);
  }
}

// ---------------- BN normalize + relu -> bf16 (vectorized x4) ----------------
__global__ void bn_norm_relu_bf16(const float* __restrict__ X, const float* __restrict__ stats,
                                  const float* __restrict__ g, const float* __restrict__ bta,
                                  __hip_bfloat16* __restrict__ obf, int M) {
  int i4 = blockIdx.x * blockDim.x + threadIdx.x;
  if (i4 * 4 >= M * FDIM) return;
  int f = (i4 * 4) & (FDIM - 1);
  f32x4 x  = *(const f32x4*)(X + (size_t)i4 * 4);
  f32x4 sm = *(const f32x4*)(stats + f);
  f32x4 sq = *(const f32x4*)(stats + FDIM + f);
  f32x4 gv = *(const f32x4*)(g + f);
  f32x4 bv = *(const f32x4*)(bta + f);
  float inv_m = 1.0f / (float)M;
  bf16x4 o;
#pragma unroll
  for (int j = 0; j < 4; j++) {
    float mean = sm[j] * inv_m;
    float var = sq[j] * inv_m - mean * mean;
    float xn = (x[j] - mean) * rsqrtf(var + EPSBN) * gv[j] + bv[j];
    __hip_bfloat16 hh = __float2bfloat16(fmaxf(xn, 0.0f));
    o[j] = *reinterpret_cast<short*>(&hh);
  }
  *(bf16x4*)((short*)obf + (size_t)i4 * 4) = o;
}

// -------- heads with BN2 normalize+relu fused in: logits, softmax, deltas --------
__global__ void heads_bn(const float* __restrict__ X2, const float* __restrict__ stats,
                         const float* __restrict__ gg, const float* __restrict__ bb,
                         const float* __restrict__ cls_w, const float* __restrict__ cls_b,
                         const float* __restrict__ dw, const float* __restrict__ db,
                         float* __restrict__ out) {
  int row = blockIdx.x * 4 + (threadIdx.x >> 6);
  int lane = threadIdx.x & 63;
  if (row >= M_ROWS) return;
  const float* xrow = X2 + (size_t)row * FDIM;
  float inv_m = 1.0f / (float)M_ROWS;
  float a[10];
#pragma unroll
  for (int j = 0; j < 10; j++) a[j] = 0.0f;
  for (int k = lane; k < FDIM; k += 64) {
    float mean = stats[k] * inv_m;
    float var = stats[FDIM + k] * inv_m - mean * mean;
    float v = fmaxf((xrow[k] - mean) * rsqrtf(var + EPSBN) * gg[k] + bb[k], 0.0f);
    a[0] += v * cls_w[k * 2 + 0];
    a[1] += v * cls_w[k * 2 + 1];
#pragma unroll
    for (int j = 0; j < 8; j++) a[2 + j] += v * dw[k * 8 + j];
  }
#pragma unroll
  for (int j = 0; j < 10; j++)
    for (int o = 32; o > 0; o >>= 1) a[j] += __shfl_xor(a[j], o, 64);
  if (lane == 0) {
    float l0 = a[0] + cls_b[0], l1 = a[1] + cls_b[1];
    out[row * 2 + 0] = l0;
    out[row * 2 + 1] = l1;
    float mx = fmaxf(l0, l1);
    float e0 = expf(l0 - mx), e1 = expf(l1 - mx);
    float inv = 1.0f / (e0 + e1);
    out[4000 + row * 2 + 0] = e0 * inv;
    out[4000 + row * 2 + 1] = e1 * inv;
#pragma unroll
    for (int j = 0; j < 8; j++) out[8000 + row * 8 + j] = a[2 + j] + db[j];
  }
}

extern "C" void kernel_launch(void* const* d_in, const int* in_sizes, int n_in,
                              void* d_out, int out_size, void* d_ws, size_t ws_size,
                              hipStream_t stream) {
  const float* rois    = (const float*)d_in[0];
  const float* p2      = (const float*)d_in[1];
  const float* p3      = (const float*)d_in[2];
  const float* p4      = (const float*)d_in[3];
  const float* p5      = (const float*)d_in[4];
  const float* conv1_w = (const float*)d_in[5];
  const float* conv1_b = (const float*)d_in[6];
  const float* bn1_g   = (const float*)d_in[7];
  const float* bn1_b   = (const float*)d_in[8];
  const float* conv2_w = (const float*)d_in[9];
  const float* conv2_b = (const float*)d_in[10];
  const float* bn2_g   = (const float*)d_in[11];
  const float* bn2_b   = (const float*)d_in[12];
  const float* cls_w   = (const float*)d_in[13];
  const float* cls_b   = (const float*)d_in[14];
  const float* delta_w = (const float*)d_in[15];
  const float* delta_b = (const float*)d_in[16];
  float* out = (float*)d_out;

  char* ws = (char*)d_ws;
  size_t off = 0;
  __hip_bfloat16* pooled = (__hip_bfloat16*)(ws + off); off += (size_t)M_ROWS * K1 * 2;   // 50,176,000
  __hip_bfloat16* w1t    = (__hip_bfloat16*)(ws + off); off += (size_t)K1 * FDIM * 2;     // 25,690,112
  __hip_bfloat16* w2t    = (__hip_bfloat16*)(ws + off); off += (size_t)FDIM * FDIM * 2;   //  2,097,152
  float* stats1          = (float*)(ws + off);          off += 2 * FDIM * 4;
  float* stats2          = (float*)(ws + off);          off += 2 * FDIM * 4;
  char*  Preg            = ws + off;                    off += (size_t)4 * MN * 4;        // 32,768,000
  // temporal aliasing:
  //  GEMM1 partials = Preg S0..S3 ; reduce1 -> x1 = S0
  //  bn_norm -> x1n in pooled region (dead after GEMM1)
  //  GEMM2 partials = Preg S0..S3 (x1 dead) ; reduce2 -> x2 = S0
  float* part1        = (float*)Preg;
  float* x1           = (float*)Preg;
  __hip_bfloat16* x1n = (__hip_bfloat16*)pooled;
  float* part2        = (float*)Preg;
  float* x2           = (float*)Preg;

  // prep: zero-stats | roi-align | transpose w1 | transpose w2 (concurrent)
  prep_kernel<<<1 + M_ROWS + 3136 + 256, 256, 0, stream>>>(
      rois, p2, p3, p4, p5, pooled, conv1_w, w1t, conv2_w, w2t, stats1);

  // GEMM1: 8-wave pipelined, split-K=4 (Kc=3136), grid 16*4*4 = 256
  gemm8w<4><<<256, 512, 0, stream>>>((const short*)pooled, (const short*)w1t, part1,
                                     M_ROWS, FDIM, K1);
  reduce_bias_stats<4><<<256, 256, 0, stream>>>(part1, conv1_b, x1, stats1, M_ROWS);

  bn_norm_relu_bf16<<<MN / 1024, 256, 0, stream>>>(x1, stats1, bn1_g, bn1_b, x1n, M_ROWS);

  // GEMM2: same pipelined kernel, split-K=4 (Kc=256), grid 256
  gemm8w<4><<<256, 512, 0, stream>>>((const short*)x1n, (const short*)w2t, part2,
                                     M_ROWS, FDIM, FDIM);
  reduce_bias_stats<4><<<256, 256, 0, stream>>>(part2, conv2_b, x2, stats2, M_ROWS);

  heads_bn<<<(M_ROWS + 3) / 4, 256, 0, stream>>>(x2, stats2, bn2_g, bn2_b,
                                                 cls_w, cls_b, delta_w, delta_b, out);

  (void)in_sizes; (void)n_in; (void)out_size; (void)ws_size;
}